// Round 7
// baseline (46.516 us; speedup 1.0000x reference)
//
#include <hip/hip_runtime.h>
#include <cmath>
#include <complex>

// ChebyUpsample: x (256, 32768) f32 -> repeat x2 -> reverse -> cheby1(8,0.05,0.5)
// 4-biquad cascade -> reverse -> y (256, 65536) f32.
// Reversed-time chunked IIR, LDS-staged, TILE-PIPELINED to break phase convoy:
//   block = 128 threads, owns 4 consecutive tiles (4096 inputs each) of a row.
//   Double-buffered LDS (2 x 16.6KB). Tile i's compute starts by ISSUING the
//   global loads for tile i+1 into registers (T14 issue-early/write-late);
//   they are scaled+ds_written only after tile i's flush -> HBM read hides
//   under compute, flush writes drain under next tile's compute.
//   Per-chunk: 32 inputs -> 64 outputs; warm-up W=128 steps from staged halo
//   (zeros past row end = exact). Per-wave barrier-free flush through the
//   wave's private LDS quarter (aliases the dead input buffer).
// Swizzle SWZ(q)=q^(((q>>6)&7)<<2): 16B-granular, bijective per 512-float
// window, identity in the halo; keeps stride-32 b128 LDS ops at the 8-cycle
// data floor. W=128 is accuracy-driven; absmax 0.0156 is the fp32 rounding
// floor (same at W=192 and W=128), truncation term ~2e-3.

struct SosC {
  float g;       // kz gain folded into staged input
  float a1[4];
  float a2[4];
};

struct G2 { float4 a, b; };   // a = s[qq..qq+3], b = s[qq+4..qq+7]

#define SWZ(q) ((q) ^ ((((q) >> 6) & 7) << 2))

__global__ __launch_bounds__(128)
void cheby_up_kernel(const float* __restrict__ x, float* __restrict__ y, SosC c) {
  constexpr int T_IN = 32768;
  constexpr int TILE = 4096;            // inputs per tile
  constexpr int BUFN = TILE + 64;       // + warm-up halo
  __shared__ __align__(16) float lbuf[2][BUFN];   // 33,280 B total

  const int row = blockIdx.x >> 1;
  const int hb  = blockIdx.x & 1;       // which 4-tile half of the row
  const int t   = threadIdx.x;          // chunk id within tile, 0..127
  const float* xrow = x + (size_t)row * T_IN;
  float*       yrow = y + (size_t)row * (size_t)(2 * T_IN);

  const float g = c.g;
  const float a10 = c.a1[0], a20 = c.a2[0];
  const float a11 = c.a1[1], a21 = c.a2[1];
  const float a12 = c.a1[2], a22 = c.a2[2];
  const float a13 = c.a1[3], a23 = c.a2[3];

  float4 r[8], h;   // in-flight staging registers for the NEXT tile

  auto issue_stage = [&](int tb) {       // issue loads; do NOT consume yet
    const float* src = xrow + TILE * tb;
    #pragma unroll
    for (int j = 0; j < 8; ++j)
      r[j] = *reinterpret_cast<const float4*>(src + 4 * t + 512 * j);
    h = make_float4(0.f, 0.f, 0.f, 0.f);
    const int gi = TILE * (tb + 1) + 4 * t;
    if (t < 16 && gi < T_IN)
      h = *reinterpret_cast<const float4*>(xrow + gi);
  };

  auto write_stage = [&](float* L) {     // consume: scale by g, swizzled write
    #pragma unroll
    for (int j = 0; j < 8; ++j) {
      const int q = 4 * t + 512 * j;
      float4 v = r[j];
      v.x *= g; v.y *= g; v.z *= g; v.w *= g;
      *reinterpret_cast<float4*>(&L[SWZ(q)]) = v;
    }
    if (t < 16) {
      float4 v = h;
      v.x *= g; v.y *= g; v.z *= g; v.w *= g;
      *reinterpret_cast<float4*>(&L[TILE + 4 * t]) = v;  // SWZ identity here
    }
  };

  // transposed direct-form II step, 4 sections (declared per-tile below)
  // ---- prologue: stage first tile ----
  issue_stage(4 * hb);
  write_stage(lbuf[0]);
  __syncthreads();

  #pragma unroll 1
  for (int i = 0; i < 4; ++i) {
    const int tb = 4 * hb + i;
    float* L = lbuf[i & 1];
    if (i < 3) issue_stage(tb + 1);      // next tile's loads fly under compute

    float z10=0.f, z20=0.f, z11=0.f, z21=0.f;
    float z12=0.f, z22=0.f, z13=0.f, z23=0.f;

    auto step = [&](float x0) -> float {
      float y0 = x0 + z10;
      z10 = fmaf(-a10, y0, fmaf(2.f, x0, z20));
      z20 = fmaf(-a20, y0, x0);
      float y1 = y0 + z11;
      z11 = fmaf(-a11, y1, fmaf(2.f, y0, z21));
      z21 = fmaf(-a21, y1, y0);
      float y2 = y1 + z12;
      z12 = fmaf(-a12, y2, fmaf(2.f, y1, z22));
      z22 = fmaf(-a22, y2, y1);
      float y3 = y2 + z13;
      z13 = fmaf(-a13, y3, fmaf(2.f, y2, z23));
      z23 = fmaf(-a23, y3, y2);
      return y3;
    };

    auto rd8 = [&](int qq) -> G2 {       // 8 consecutive staged samples
      G2 v;
      v.a = *reinterpret_cast<const float4*>(&L[SWZ(qq)]);
      v.b = *reinterpret_cast<const float4*>(&L[SWZ(qq + 4)]);
      return v;
    };

    auto steps16 = [&](const G2& v) {    // reversed time = forward descending
      float s;
      s = v.b.w; step(s); step(s);
      s = v.b.z; step(s); step(s);
      s = v.b.y; step(s); step(s);
      s = v.b.x; step(s); step(s);
      s = v.a.w; step(s); step(s);
      s = v.a.z; step(s); step(s);
      s = v.a.y; step(s); step(s);
      s = v.a.x; step(s); step(s);
    };

    // ---- warm-up: 8 groups (64 inputs = 128 steps), offsets [32t+32, 32t+96)
    G2 cur = rd8(32 * t + 88);
    #pragma unroll
    for (int wg = 7; wg >= 1; --wg) {
      G2 nxt = rd8(32 * t + 32 + 8 * (wg - 1));
      steps16(cur);
      cur = nxt;
    }
    // own 32 inputs -> registers; L input data dead after this
    G2 g3 = rd8(32 * t + 24);
    G2 g2 = rd8(32 * t + 16);
    G2 g1 = rd8(32 * t + 8);
    G2 g0 = rd8(32 * t);
    steps16(cur);                        // last warm group (offset 32)
    __syncthreads();                     // ALL reads of L done; safe to alias

    const int w = t >> 6;                // wave id 0..1
    const int l = t & 63;
    const int Q = 2048 * w;              // wave's private LDS quarter (8KB)

    float o[32];                         // static indices only

    auto flush32 = [&](int half) {       // per-wave barrier-free transpose+store
      #pragma unroll
      for (int ii = 0; ii < 8; ++ii) {
        int q = Q + 32 * l + 4 * ii;
        *reinterpret_cast<float4*>(&L[SWZ(q)]) =
            make_float4(o[4*ii], o[4*ii+1], o[4*ii+2], o[4*ii+3]);
      }
      float* yG = yrow + 8192 * tb + 4096 * w + half;
      #pragma unroll
      for (int j = 0; j < 8; ++j) {
        int local = 4 * l + 256 * j;               // 0..2047
        float4 v = *reinterpret_cast<const float4*>(&L[SWZ(Q + local)]);
        int c64 = local >> 5;                      // chunk lane 0..63
        int m   = local & 31;
        *reinterpret_cast<float4*>(yG + 64 * c64 + m) = v;  // 128B dense runs
      }
    };

    // ---- phase A: outputs [32,64) from inputs [16,32) (forward descending)
    {
      float s;
      s = g3.b.w; o[31] = step(s); o[30] = step(s);
      s = g3.b.z; o[29] = step(s); o[28] = step(s);
      s = g3.b.y; o[27] = step(s); o[26] = step(s);
      s = g3.b.x; o[25] = step(s); o[24] = step(s);
      s = g3.a.w; o[23] = step(s); o[22] = step(s);
      s = g3.a.z; o[21] = step(s); o[20] = step(s);
      s = g3.a.y; o[19] = step(s); o[18] = step(s);
      s = g3.a.x; o[17] = step(s); o[16] = step(s);
      s = g2.b.w; o[15] = step(s); o[14] = step(s);
      s = g2.b.z; o[13] = step(s); o[12] = step(s);
      s = g2.b.y; o[11] = step(s); o[10] = step(s);
      s = g2.b.x; o[9]  = step(s); o[8]  = step(s);
      s = g2.a.w; o[7]  = step(s); o[6]  = step(s);
      s = g2.a.z; o[5]  = step(s); o[4]  = step(s);
      s = g2.a.y; o[3]  = step(s); o[2]  = step(s);
      s = g2.a.x; o[1]  = step(s); o[0]  = step(s);
    }
    flush32(32);

    // ---- phase B: outputs [0,32) from inputs [0,16) ----
    {
      float s;
      s = g1.b.w; o[31] = step(s); o[30] = step(s);
      s = g1.b.z; o[29] = step(s); o[28] = step(s);
      s = g1.b.y; o[27] = step(s); o[26] = step(s);
      s = g1.b.x; o[25] = step(s); o[24] = step(s);
      s = g1.a.w; o[23] = step(s); o[22] = step(s);
      s = g1.a.z; o[21] = step(s); o[20] = step(s);
      s = g1.a.y; o[19] = step(s); o[18] = step(s);
      s = g1.a.x; o[17] = step(s); o[16] = step(s);
      s = g0.b.w; o[15] = step(s); o[14] = step(s);
      s = g0.b.z; o[13] = step(s); o[12] = step(s);
      s = g0.b.y; o[11] = step(s); o[10] = step(s);
      s = g0.b.x; o[9]  = step(s); o[8]  = step(s);
      s = g0.a.w; o[7]  = step(s); o[6]  = step(s);
      s = g0.a.z; o[5]  = step(s); o[4]  = step(s);
      s = g0.a.y; o[3]  = step(s); o[2]  = step(s);
      s = g0.a.x; o[1]  = step(s); o[0]  = step(s);
    }
    flush32(0);

    if (i < 3) {
      write_stage(lbuf[(i & 1) ^ 1]);    // consume prefetched loads -> other buf
      __syncthreads();                   // staged data visible to all waves
    }
  }
}

// Host-side replication of _cheby1_sos(8, 0.05, 0.5) in double precision.
static SosC compute_coefs() {
  const int N = 8;
  const double rp = 0.05, Wn = 0.5;
  const double PI = 3.14159265358979323846;
  double eps = std::sqrt(std::pow(10.0, 0.1 * rp) - 1.0);
  double mu = std::asinh(1.0 / eps) / (double)N;
  std::complex<double> p[8];
  std::complex<double> prodNegP(1.0, 0.0);
  int idx = 0;
  for (int m = -N + 1; m < N; m += 2) {
    double theta = PI * (double)m / (2.0 * N);
    std::complex<double> pp = -std::sinh(std::complex<double>(mu, theta));
    p[idx++] = pp;
    prodNegP *= -pp;
  }
  double k = prodNegP.real();
  k /= std::sqrt(1.0 + eps * eps);          // even N
  const double fs = 2.0;
  double warped = 2.0 * fs * std::tan(PI * Wn / fs);
  for (int i = 0; i < 8; i++) p[i] *= warped;
  k *= std::pow(warped, (double)N);
  const double fs2 = 2.0 * fs;
  std::complex<double> prodDen(1.0, 0.0);
  for (int i = 0; i < 8; i++) prodDen *= (fs2 - p[i]);
  double kz = k * (1.0 / prodDen).real();

  SosC c;
  int s = 0;
  for (int i = 0; i < 8; i++) {
    std::complex<double> pz = (fs2 + p[i]) / (fs2 - p[i]);
    if (pz.imag() > 0.0) {                  // same selection order as numpy
      c.a1[s] = (float)(-2.0 * pz.real());
      c.a2[s] = (float)std::norm(pz);       // |pz|^2
      s++;
    }
  }
  c.g = (float)kz;
  return c;
}

extern "C" void kernel_launch(void* const* d_in, const int* in_sizes, int n_in,
                              void* d_out, int out_size, void* d_ws, size_t ws_size,
                              hipStream_t stream) {
  const float* x = (const float*)d_in[0];
  float* y = (float*)d_out;
  SosC c = compute_coefs();
  int rows = in_sizes[0] / 32768;   // 256
  // 2 blocks/row x 4 pipelined tiles each; 512 blocks of 128 threads
  cheby_up_kernel<<<2 * rows, 128, 0, stream>>>(x, y, c);
}

// Round 8
// 30.919 us; speedup vs baseline: 1.5044x; 1.5044x over previous
//
#include <hip/hip_runtime.h>
#include <cmath>
#include <complex>

// ChebyUpsample: x (256, 32768) f32 -> repeat x2 -> reverse -> cheby1(8,0.05,0.5)
// 4-biquad cascade -> reverse -> y (256, 65536) f32.
// Reversed-time chunked IIR. SINGLE-WAVE blocks for generational overlap:
//   block = 64 threads (1 wave) = 64 chunks of 32 inputs; tile = 2048 (+64
//   halo) = 8.45KB LDS. Grid = 4096 blocks -> ~16 sequential generations/CU
//   (16 co-resident: VGPR<=128 and LDS 135KB/CU), so store drain of one
//   generation overlaps staging/compute of the next -> max(phases), not sum
//   (R6 lesson: one co-resident generation = sum of phases = 31us).
//   Zero __syncthreads: all LDS hazards are same-wave (DS-pipe ordered).
//   Warm-up W=128 steps from staged halo (zeros past row end = exact).
//   Flush: per-wave transpose through the (dead) input buffer, 128B-dense
//   coalesced stores. Swizzle SWZ(q)=q^(((q>>6)&7)<<2): 16B-granular,
//   bijective per 512-float window, identity in halo; stride-32 b128 reads
//   stay at the 8-access bank floor.

struct SosC {
  float g;       // kz gain folded into staged input
  float a1[4];
  float a2[4];
};

struct G2 { float4 a, b; };   // a = s[qq..qq+3], b = s[qq+4..qq+7]

#define SWZ(q) ((q) ^ ((((q) >> 6) & 7) << 2))

__global__ __launch_bounds__(64)
void cheby_up_kernel(const float* __restrict__ x, float* __restrict__ y, SosC c) {
  constexpr int T_IN = 32768;
  constexpr int TILE = 2048;
  __shared__ __align__(16) float lbuf[TILE + 64];   // 8448 B

  const int row = blockIdx.x >> 4;
  const int tb  = blockIdx.x & 15;      // tile index within row
  const int l   = threadIdx.x;          // lane = chunk id, 0..63
  const float* xrow = x + (size_t)row * T_IN;
  float*       yrow = y + (size_t)row * (size_t)(2 * T_IN);
  const int tbase = TILE * tb;

  const float g = c.g;

  // ---- stage tile, coalesced, pre-scaled by g (8 x float4 per lane) ----
  #pragma unroll
  for (int j = 0; j < 8; ++j) {
    int q = 4 * l + 256 * j;                        // 0..2047
    float4 v = *reinterpret_cast<const float4*>(xrow + tbase + q);
    v.x *= g; v.y *= g; v.z *= g; v.w *= g;
    *reinterpret_cast<float4*>(&lbuf[SWZ(q)]) = v;
  }
  if (l < 16) {                                     // 64-float halo
    int q = TILE + 4 * l;                           // SWZ identity here
    int gi = tbase + q;
    float4 v = make_float4(0.f, 0.f, 0.f, 0.f);
    if (gi < T_IN) {
      v = *reinterpret_cast<const float4*>(xrow + gi);
      v.x *= g; v.y *= g; v.z *= g; v.w *= g;
    }
    *reinterpret_cast<float4*>(&lbuf[q]) = v;
  }
  // single wave: DS reads below are ordered after these writes (lgkmcnt)

  const float a10 = c.a1[0], a20 = c.a2[0];
  const float a11 = c.a1[1], a21 = c.a2[1];
  const float a12 = c.a1[2], a22 = c.a2[2];
  const float a13 = c.a1[3], a23 = c.a2[3];

  // transposed direct-form II states, 4 sections
  float z10=0.f, z20=0.f, z11=0.f, z21=0.f;
  float z12=0.f, z22=0.f, z13=0.f, z23=0.f;

  auto step = [&](float x0) -> float {
    float y0 = x0 + z10;
    z10 = fmaf(-a10, y0, fmaf(2.f, x0, z20));
    z20 = fmaf(-a20, y0, x0);
    float y1 = y0 + z11;
    z11 = fmaf(-a11, y1, fmaf(2.f, y0, z21));
    z21 = fmaf(-a21, y1, y0);
    float y2 = y1 + z12;
    z12 = fmaf(-a12, y2, fmaf(2.f, y1, z22));
    z22 = fmaf(-a22, y2, y1);
    float y3 = y2 + z13;
    z13 = fmaf(-a13, y3, fmaf(2.f, y2, z23));
    z23 = fmaf(-a23, y3, y2);
    return y3;
  };

  auto rd8 = [&](int qq) -> G2 {     // 8 consecutive staged samples
    G2 r;
    r.a = *reinterpret_cast<const float4*>(&lbuf[SWZ(qq)]);
    r.b = *reinterpret_cast<const float4*>(&lbuf[SWZ(qq + 4)]);
    return r;
  };

  // 16 filter steps over 8 inputs, reversed-time order = forward descending
  auto steps16 = [&](const G2& v) {
    float s;
    s = v.b.w; step(s); step(s);
    s = v.b.z; step(s); step(s);
    s = v.b.y; step(s); step(s);
    s = v.b.x; step(s); step(s);
    s = v.a.w; step(s); step(s);
    s = v.a.z; step(s); step(s);
    s = v.a.y; step(s); step(s);
    s = v.a.x; step(s); step(s);
  };

  // ---- warm-up: 8 groups (64 inputs = 128 steps), offsets [32l+32, 32l+96) ----
  G2 cur = rd8(32 * l + 88);
  #pragma unroll
  for (int wg = 7; wg >= 1; --wg) {
    G2 nxt = rd8(32 * l + 32 + 8 * (wg - 1));
    steps16(cur);
    cur = nxt;
  }

  // own 32 inputs -> registers; lbuf becomes dead for reads after this
  G2 g3 = rd8(32 * l + 24);
  G2 g2 = rd8(32 * l + 16);
  G2 g1 = rd8(32 * l + 8);
  G2 g0 = rd8(32 * l);
  steps16(cur);               // last warm group (offset 32)

  float o[32];                // static indices only (fully unrolled)

  // per-wave transpose+store of 32 outputs at chunk offset `half`
  auto flush32 = [&](int half) {
    #pragma unroll
    for (int i = 0; i < 8; ++i) {
      int q = 32 * l + 4 * i;
      *reinterpret_cast<float4*>(&lbuf[SWZ(q)]) =
          make_float4(o[4*i], o[4*i+1], o[4*i+2], o[4*i+3]);
    }
    float* yG = yrow + 2 * tbase + half;
    #pragma unroll
    for (int j = 0; j < 8; ++j) {
      int local = 4 * l + 256 * j;                    // 0..2047
      float4 v = *reinterpret_cast<const float4*>(&lbuf[SWZ(local)]);
      int c64 = local >> 5;                           // source chunk 0..63
      int m   = local & 31;                           // offset within half
      *reinterpret_cast<float4*>(yG + 64 * c64 + m) = v;  // 128B dense runs
    }
  };

  // ---- phase A: outputs [32,64) from inputs [16,32) (forward descending) ----
  {
    float s;
    s = g3.b.w; o[31] = step(s); o[30] = step(s);
    s = g3.b.z; o[29] = step(s); o[28] = step(s);
    s = g3.b.y; o[27] = step(s); o[26] = step(s);
    s = g3.b.x; o[25] = step(s); o[24] = step(s);
    s = g3.a.w; o[23] = step(s); o[22] = step(s);
    s = g3.a.z; o[21] = step(s); o[20] = step(s);
    s = g3.a.y; o[19] = step(s); o[18] = step(s);
    s = g3.a.x; o[17] = step(s); o[16] = step(s);
    s = g2.b.w; o[15] = step(s); o[14] = step(s);
    s = g2.b.z; o[13] = step(s); o[12] = step(s);
    s = g2.b.y; o[11] = step(s); o[10] = step(s);
    s = g2.b.x; o[9]  = step(s); o[8]  = step(s);
    s = g2.a.w; o[7]  = step(s); o[6]  = step(s);
    s = g2.a.z; o[5]  = step(s); o[4]  = step(s);
    s = g2.a.y; o[3]  = step(s); o[2]  = step(s);
    s = g2.a.x; o[1]  = step(s); o[0]  = step(s);
  }
  flush32(32);

  // ---- phase B: outputs [0,32) from inputs [0,16) ----
  {
    float s;
    s = g1.b.w; o[31] = step(s); o[30] = step(s);
    s = g1.b.z; o[29] = step(s); o[28] = step(s);
    s = g1.b.y; o[27] = step(s); o[26] = step(s);
    s = g1.b.x; o[25] = step(s); o[24] = step(s);
    s = g1.a.w; o[23] = step(s); o[22] = step(s);
    s = g1.a.z; o[21] = step(s); o[20] = step(s);
    s = g1.a.y; o[19] = step(s); o[18] = step(s);
    s = g1.a.x; o[17] = step(s); o[16] = step(s);
    s = g0.b.w; o[15] = step(s); o[14] = step(s);
    s = g0.b.z; o[13] = step(s); o[12] = step(s);
    s = g0.b.y; o[11] = step(s); o[10] = step(s);
    s = g0.b.x; o[9]  = step(s); o[8]  = step(s);
    s = g0.a.w; o[7]  = step(s); o[6]  = step(s);
    s = g0.a.z; o[5]  = step(s); o[4]  = step(s);
    s = g0.a.y; o[3]  = step(s); o[2]  = step(s);
    s = g0.a.x; o[1]  = step(s); o[0]  = step(s);
  }
  flush32(0);
}

// Host-side replication of _cheby1_sos(8, 0.05, 0.5) in double precision.
static SosC compute_coefs() {
  const int N = 8;
  const double rp = 0.05, Wn = 0.5;
  const double PI = 3.14159265358979323846;
  double eps = std::sqrt(std::pow(10.0, 0.1 * rp) - 1.0);
  double mu = std::asinh(1.0 / eps) / (double)N;
  std::complex<double> p[8];
  std::complex<double> prodNegP(1.0, 0.0);
  int idx = 0;
  for (int m = -N + 1; m < N; m += 2) {
    double theta = PI * (double)m / (2.0 * N);
    std::complex<double> pp = -std::sinh(std::complex<double>(mu, theta));
    p[idx++] = pp;
    prodNegP *= -pp;
  }
  double k = prodNegP.real();
  k /= std::sqrt(1.0 + eps * eps);          // even N
  const double fs = 2.0;
  double warped = 2.0 * fs * std::tan(PI * Wn / fs);
  for (int i = 0; i < 8; i++) p[i] *= warped;
  k *= std::pow(warped, (double)N);
  const double fs2 = 2.0 * fs;
  std::complex<double> prodDen(1.0, 0.0);
  for (int i = 0; i < 8; i++) prodDen *= (fs2 - p[i]);
  double kz = k * (1.0 / prodDen).real();

  SosC c;
  int s = 0;
  for (int i = 0; i < 8; i++) {
    std::complex<double> pz = (fs2 + p[i]) / (fs2 - p[i]);
    if (pz.imag() > 0.0) {                  // same selection order as numpy
      c.a1[s] = (float)(-2.0 * pz.real());
      c.a2[s] = (float)std::norm(pz);       // |pz|^2
      s++;
    }
  }
  c.g = (float)kz;
  return c;
}

extern "C" void kernel_launch(void* const* d_in, const int* in_sizes, int n_in,
                              void* d_out, int out_size, void* d_ws, size_t ws_size,
                              hipStream_t stream) {
  const float* x = (const float*)d_in[0];
  float* y = (float*)d_out;
  SosC c = compute_coefs();
  int rows = in_sizes[0] / 32768;   // 256
  // 16 single-wave tiles per row -> 4096 blocks of 64 threads
  cheby_up_kernel<<<16 * rows, 64, 0, stream>>>(x, y, c);
}

// Round 9
// 26.632 us; speedup vs baseline: 1.7466x; 1.1610x over previous
//
#include <hip/hip_runtime.h>
#include <cmath>
#include <complex>

// ChebyUpsample: x (256, 32768) f32 -> repeat x2 -> reverse -> cheby1(8,0.05,0.5)
// 4-biquad cascade -> reverse -> y (256, 65536) f32.
// Reversed-time chunked IIR, single-wave blocks (R8 structure), with the
// 128-step serial warm-up replaced by a PRECOMPUTED LINEAR PREDICTOR:
//   z_main = sum_j w_j * x[je+32+j],  w_j = A^{2j}(A+I)b  (host, double).
// Weights (64x8 floats, 2KB) ride in kernarg -> s_load broadcast -> SGPR
// operands of v_fmac; 512 independent FMAs replace 2048 serial VALU ops.
// Everything else identical to verified R8: tile=2048(+64 halo)=8.45KB LDS,
// 64 chunks x 32 inputs -> 64 outputs, SWZ'd LDS, per-wave barrier-free
// flush through the dead input buffer, 128B-dense coalesced stores.

struct KArgs {
  float g;          // kz gain folded into staged input
  float a1[4];
  float a2[4];
  float w[64][8];   // state predictor taps, state order z10,z20,z11,...,z23
};

struct G2 { float4 a, b; };   // a = s[qq..qq+3], b = s[qq+4..qq+7]

#define SWZ(q) ((q) ^ ((((q) >> 6) & 7) << 2))

__global__ __launch_bounds__(64)
void cheby_up_kernel(const float* __restrict__ x, float* __restrict__ y, KArgs c) {
  constexpr int T_IN = 32768;
  constexpr int TILE = 2048;
  __shared__ __align__(16) float lbuf[TILE + 64];   // 8448 B

  const int row = blockIdx.x >> 4;
  const int tb  = blockIdx.x & 15;      // tile index within row
  const int l   = threadIdx.x;          // lane = chunk id, 0..63
  const float* xrow = x + (size_t)row * T_IN;
  float*       yrow = y + (size_t)row * (size_t)(2 * T_IN);
  const int tbase = TILE * tb;

  const float g = c.g;

  // ---- stage tile, coalesced, pre-scaled by g (8 x float4 per lane) ----
  #pragma unroll
  for (int j = 0; j < 8; ++j) {
    int q = 4 * l + 256 * j;                        // 0..2047
    float4 v = *reinterpret_cast<const float4*>(xrow + tbase + q);
    v.x *= g; v.y *= g; v.z *= g; v.w *= g;
    *reinterpret_cast<float4*>(&lbuf[SWZ(q)]) = v;
  }
  if (l < 16) {                                     // 64-float halo
    int q = TILE + 4 * l;                           // SWZ identity here
    int gi = tbase + q;
    float4 v = make_float4(0.f, 0.f, 0.f, 0.f);
    if (gi < T_IN) {
      v = *reinterpret_cast<const float4*>(xrow + gi);
      v.x *= g; v.y *= g; v.z *= g; v.w *= g;
    }
    *reinterpret_cast<float4*>(&lbuf[q]) = v;
  }
  // single wave: DS reads below are ordered after these writes (lgkmcnt)

  auto rd8 = [&](int qq) -> G2 {     // 8 consecutive staged samples
    G2 r;
    r.a = *reinterpret_cast<const float4*>(&lbuf[SWZ(qq)]);
    r.b = *reinterpret_cast<const float4*>(&lbuf[SWZ(qq + 4)]);
    return r;
  };

  // own 32 inputs -> registers (independent of warm region; issue early)
  G2 g3 = rd8(32 * l + 24);
  G2 g2 = rd8(32 * l + 16);
  G2 g1 = rd8(32 * l + 8);
  G2 g0 = rd8(32 * l);

  // ---- linear-predictor warm-up: z = sum_{j=0..63} w_j * staged[32l+32+j] ----
  float ac0=0.f, ac1=0.f, ac2=0.f, ac3=0.f, ac4=0.f, ac5=0.f, ac6=0.f, ac7=0.f;
  #define TAP(jj, xx)                      \
    ac0 = fmaf(c.w[jj][0], (xx), ac0);     \
    ac1 = fmaf(c.w[jj][1], (xx), ac1);     \
    ac2 = fmaf(c.w[jj][2], (xx), ac2);     \
    ac3 = fmaf(c.w[jj][3], (xx), ac3);     \
    ac4 = fmaf(c.w[jj][4], (xx), ac4);     \
    ac5 = fmaf(c.w[jj][5], (xx), ac5);     \
    ac6 = fmaf(c.w[jj][6], (xx), ac6);     \
    ac7 = fmaf(c.w[jj][7], (xx), ac7);
  #pragma unroll
  for (int wg = 0; wg < 8; ++wg) {
    G2 v = rd8(32 * l + 32 + 8 * wg);
    const int j0 = 8 * wg;                 // constant after unroll
    TAP(j0 + 0, v.a.x); TAP(j0 + 1, v.a.y);
    TAP(j0 + 2, v.a.z); TAP(j0 + 3, v.a.w);
    TAP(j0 + 4, v.b.x); TAP(j0 + 5, v.b.y);
    TAP(j0 + 6, v.b.z); TAP(j0 + 7, v.b.w);
  }
  #undef TAP

  const float a10 = c.a1[0], a20 = c.a2[0];
  const float a11 = c.a1[1], a21 = c.a2[1];
  const float a12 = c.a1[2], a22 = c.a2[2];
  const float a13 = c.a1[3], a23 = c.a2[3];

  // transposed direct-form II states seeded by the predictor
  float z10=ac0, z20=ac1, z11=ac2, z21=ac3;
  float z12=ac4, z22=ac5, z13=ac6, z23=ac7;

  auto step = [&](float x0) -> float {
    float y0 = x0 + z10;
    z10 = fmaf(-a10, y0, fmaf(2.f, x0, z20));
    z20 = fmaf(-a20, y0, x0);
    float y1 = y0 + z11;
    z11 = fmaf(-a11, y1, fmaf(2.f, y0, z21));
    z21 = fmaf(-a21, y1, y0);
    float y2 = y1 + z12;
    z12 = fmaf(-a12, y2, fmaf(2.f, y1, z22));
    z22 = fmaf(-a22, y2, y1);
    float y3 = y2 + z13;
    z13 = fmaf(-a13, y3, fmaf(2.f, y2, z23));
    z23 = fmaf(-a23, y3, y2);
    return y3;
  };

  float o[32];                // static indices only (fully unrolled)

  // per-wave transpose+store of 32 outputs at chunk offset `half`
  auto flush32 = [&](int half) {
    #pragma unroll
    for (int i = 0; i < 8; ++i) {
      int q = 32 * l + 4 * i;
      *reinterpret_cast<float4*>(&lbuf[SWZ(q)]) =
          make_float4(o[4*i], o[4*i+1], o[4*i+2], o[4*i+3]);
    }
    float* yG = yrow + 2 * tbase + half;
    #pragma unroll
    for (int j = 0; j < 8; ++j) {
      int local = 4 * l + 256 * j;                    // 0..2047
      float4 v = *reinterpret_cast<const float4*>(&lbuf[SWZ(local)]);
      int c64 = local >> 5;                           // source chunk 0..63
      int m   = local & 31;                           // offset within half
      *reinterpret_cast<float4*>(yG + 64 * c64 + m) = v;  // 128B dense runs
    }
  };

  // ---- phase A: outputs [32,64) from inputs [16,32) (forward descending) ----
  {
    float s;
    s = g3.b.w; o[31] = step(s); o[30] = step(s);
    s = g3.b.z; o[29] = step(s); o[28] = step(s);
    s = g3.b.y; o[27] = step(s); o[26] = step(s);
    s = g3.b.x; o[25] = step(s); o[24] = step(s);
    s = g3.a.w; o[23] = step(s); o[22] = step(s);
    s = g3.a.z; o[21] = step(s); o[20] = step(s);
    s = g3.a.y; o[19] = step(s); o[18] = step(s);
    s = g3.a.x; o[17] = step(s); o[16] = step(s);
    s = g2.b.w; o[15] = step(s); o[14] = step(s);
    s = g2.b.z; o[13] = step(s); o[12] = step(s);
    s = g2.b.y; o[11] = step(s); o[10] = step(s);
    s = g2.b.x; o[9]  = step(s); o[8]  = step(s);
    s = g2.a.w; o[7]  = step(s); o[6]  = step(s);
    s = g2.a.z; o[5]  = step(s); o[4]  = step(s);
    s = g2.a.y; o[3]  = step(s); o[2]  = step(s);
    s = g2.a.x; o[1]  = step(s); o[0]  = step(s);
  }
  flush32(32);

  // ---- phase B: outputs [0,32) from inputs [0,16) ----
  {
    float s;
    s = g1.b.w; o[31] = step(s); o[30] = step(s);
    s = g1.b.z; o[29] = step(s); o[28] = step(s);
    s = g1.b.y; o[27] = step(s); o[26] = step(s);
    s = g1.b.x; o[25] = step(s); o[24] = step(s);
    s = g1.a.w; o[23] = step(s); o[22] = step(s);
    s = g1.a.z; o[21] = step(s); o[20] = step(s);
    s = g1.a.y; o[19] = step(s); o[18] = step(s);
    s = g1.a.x; o[17] = step(s); o[16] = step(s);
    s = g0.b.w; o[15] = step(s); o[14] = step(s);
    s = g0.b.z; o[13] = step(s); o[12] = step(s);
    s = g0.b.y; o[11] = step(s); o[10] = step(s);
    s = g0.b.x; o[9]  = step(s); o[8]  = step(s);
    s = g0.a.w; o[7]  = step(s); o[6]  = step(s);
    s = g0.a.z; o[5]  = step(s); o[4]  = step(s);
    s = g0.a.y; o[3]  = step(s); o[2]  = step(s);
    s = g0.a.x; o[1]  = step(s); o[0]  = step(s);
  }
  flush32(0);
}

// ---------------- host side ----------------

// one filter step in double, state order z10,z20,z11,z21,z12,z22,z13,z23
static void step_d(double z[8], double xx, const double A1[4], const double A2[4]) {
  double u = xx;
  double v = u + z[0];
  double n0 = 2.0*u - A1[0]*v + z[1];
  double n1 = u - A2[0]*v;
  u = v; v = u + z[2];
  double n2 = 2.0*u - A1[1]*v + z[3];
  double n3 = u - A2[1]*v;
  u = v; v = u + z[4];
  double n4 = 2.0*u - A1[2]*v + z[5];
  double n5 = u - A2[2]*v;
  u = v; v = u + z[6];
  double n6 = 2.0*u - A1[3]*v + z[7];
  double n7 = u - A2[3]*v;
  z[0]=n0; z[1]=n1; z[2]=n2; z[3]=n3; z[4]=n4; z[5]=n5; z[6]=n6; z[7]=n7;
}

static void matvec8(const double A[8][8], const double v[8], double out[8]) {
  for (int r = 0; r < 8; ++r) {
    double s = 0.0;
    for (int k = 0; k < 8; ++k) s += A[r][k] * v[k];
    out[r] = s;
  }
}

// Replicates _cheby1_sos(8, 0.05, 0.5) and builds predictor taps.
static KArgs compute_args() {
  const int N = 8;
  const double rp = 0.05, Wn = 0.5;
  const double PI = 3.14159265358979323846;
  double eps = std::sqrt(std::pow(10.0, 0.1 * rp) - 1.0);
  double mu = std::asinh(1.0 / eps) / (double)N;
  std::complex<double> p[8];
  std::complex<double> prodNegP(1.0, 0.0);
  int idx = 0;
  for (int m = -N + 1; m < N; m += 2) {
    double theta = PI * (double)m / (2.0 * N);
    std::complex<double> pp = -std::sinh(std::complex<double>(mu, theta));
    p[idx++] = pp;
    prodNegP *= -pp;
  }
  double k = prodNegP.real();
  k /= std::sqrt(1.0 + eps * eps);          // even N
  const double fs = 2.0;
  double warped = 2.0 * fs * std::tan(PI * Wn / fs);
  for (int i = 0; i < 8; i++) p[i] *= warped;
  k *= std::pow(warped, (double)N);
  const double fs2 = 2.0 * fs;
  std::complex<double> prodDen(1.0, 0.0);
  for (int i = 0; i < 8; i++) prodDen *= (fs2 - p[i]);
  double kz = k * (1.0 / prodDen).real();

  KArgs c;
  double A1d[4], A2d[4];
  int s = 0;
  for (int i = 0; i < 8; i++) {
    std::complex<double> pz = (fs2 + p[i]) / (fs2 - p[i]);
    if (pz.imag() > 0.0) {                  // same selection order as numpy
      A1d[s] = -2.0 * pz.real();
      A2d[s] = std::norm(pz);               // |pz|^2
      c.a1[s] = (float)A1d[s];
      c.a2[s] = (float)A2d[s];
      s++;
    }
  }
  c.g = (float)kz;

  // build A (8x8) and b from the step function
  double A[8][8], bv[8];
  for (int i = 0; i < 8; ++i) {
    double z[8] = {0,0,0,0,0,0,0,0};
    z[i] = 1.0;
    step_d(z, 0.0, A1d, A2d);
    for (int r = 0; r < 8; ++r) A[r][i] = z[r];
  }
  {
    double z[8] = {0,0,0,0,0,0,0,0};
    step_d(z, 1.0, A1d, A2d);
    for (int r = 0; r < 8; ++r) bv[r] = z[r];
  }
  // w_0 = (A+I)b ; w_{j+1} = A^2 w_j
  double w[8], t[8];
  matvec8(A, bv, t);
  for (int r = 0; r < 8; ++r) w[r] = t[r] + bv[r];
  for (int j = 0; j < 64; ++j) {
    for (int r = 0; r < 8; ++r) c.w[j][r] = (float)w[r];
    matvec8(A, w, t);
    matvec8(A, t, w);
  }
  return c;
}

extern "C" void kernel_launch(void* const* d_in, const int* in_sizes, int n_in,
                              void* d_out, int out_size, void* d_ws, size_t ws_size,
                              hipStream_t stream) {
  const float* x = (const float*)d_in[0];
  float* y = (float*)d_out;
  KArgs c = compute_args();
  int rows = in_sizes[0] / 32768;   // 256
  // 16 single-wave tiles per row -> 4096 blocks of 64 threads
  cheby_up_kernel<<<16 * rows, 64, 0, stream>>>(x, y, c);
}